// Round 2
// baseline (273.526 us; speedup 1.0000x reference)
//
#include <hip/hip_runtime.h>
#include <hip/hip_bf16.h>

#define B_    4
#define NQ    512
#define NKV   2048
#define NT    2560     // NKV + NQ
#define DIM_  1024
#define HEADS 16
#define DH    64
#define NSEQT 10240    // B_*NT
// SCALE * log2(e): attention uses raw exp2
#define SCALE_Q_L2E 0.18033688011112042f

typedef short bf16x8 __attribute__((ext_vector_type(8)));
typedef float f32x4  __attribute__((ext_vector_type(4)));
typedef __hip_bfloat16 bf16;

// async global->LDS, 16B per lane. Global side may be a per-lane gather;
// LDS side is wave-uniform base + lane*16.
__device__ inline void gll16(const bf16* g, bf16* l) {
  __builtin_amdgcn_global_load_lds(
      (const __attribute__((address_space(1))) unsigned int*)g,
      (__attribute__((address_space(3))) unsigned int*)l, 16, 0, 0);
}

#define VMCNT(n) asm volatile("s_waitcnt vmcnt(" #n ")" ::: "memory")
#define BAR() __builtin_amdgcn_s_barrier()

// ---------------------------------------------- fused LayerNorm + weight^T
// blocks [0, B_*NT): LN rows -> X.  blocks [B_*NT, +1024): 4x trw 64x64 tiles.
__global__ __launch_bounds__(256) void prep_kernel(
    const float* __restrict__ query, const float* __restrict__ kv,
    const float* __restrict__ lgq, const float* __restrict__ lbq,
    const float* __restrict__ lgkv, const float* __restrict__ lbkv,
    bf16* __restrict__ X,
    const float* __restrict__ W0, const float* __restrict__ W1,
    const float* __restrict__ W2, const float* __restrict__ W3,
    bf16* __restrict__ T0, bf16* __restrict__ T1,
    bf16* __restrict__ T2, bf16* __restrict__ T3)
{
  __shared__ __align__(16) char psm[9216];
  const int t = threadIdx.x;
  const int blkid = blockIdx.x;
  if (blkid < B_*NT) {
    float* sh = (float*)psm;
    int b = blkid / NT, r = blkid % NT;
    const float *src, *g, *bb;
    if (r < NKV) { src = kv    + ((size_t)b*NKV + r)*DIM_;      g = lgkv; bb = lbkv; }
    else         { src = query + ((size_t)b*NQ + (r-NKV))*DIM_; g = lgq;  bb = lbq;  }
    float4 v = ((const float4*)src)[t];
    float s  = v.x+v.y+v.z+v.w;
    float s2 = v.x*v.x+v.y*v.y+v.z*v.z+v.w*v.w;
    #pragma unroll
    for (int m=1;m<64;m<<=1){ s += __shfl_xor(s,m,64); s2 += __shfl_xor(s2,m,64); }
    int wave=t>>6, lane=t&63;
    if(lane==0){ sh[wave]=s; sh[4+wave]=s2; }
    __syncthreads();
    s  = sh[0]+sh[1]+sh[2]+sh[3];
    s2 = sh[4]+sh[5]+sh[6]+sh[7];
    float mu = s*(1.0f/DIM_);
    float rs = rsqrtf(s2*(1.0f/DIM_) - mu*mu + 1e-5f);
    float4 gg = ((const float4*)g)[t];
    float4 b4 = ((const float4*)bb)[t];
    bf16* dst = X + (size_t)blkid*DIM_ + t*4;
    dst[0]=__float2bfloat16((v.x-mu)*rs*gg.x + b4.x);
    dst[1]=__float2bfloat16((v.y-mu)*rs*gg.y + b4.y);
    dst[2]=__float2bfloat16((v.z-mu)*rs*gg.z + b4.z);
    dst[3]=__float2bfloat16((v.w-mu)*rs*gg.w + b4.w);
  } else {
    int l = blkid - B_*NT;
    const float* W; bf16* Wt;
    switch (l>>8) {
      case 0: W=W0; Wt=T0; break;
      case 1: W=W1; Wt=T1; break;
      case 2: W=W2; Wt=T2; break;
      default: W=W3; Wt=T3; break;
    }
    int rem = l & 255;
    int k0 = (rem&15)*64, n0 = (rem>>4)*64;
    bf16* Ws = (bf16*)psm;            // 64 x 72
    int kr = t>>2, nseg = (t&3)*16;
    const float4* s4 = (const float4*)(W + (size_t)(k0+kr)*DIM_ + n0 + nseg);
    union { uint4 u[2]; bf16 h[16]; } pk;
    #pragma unroll
    for (int j=0;j<4;j++){
      float4 v = s4[j];
      pk.h[j*4+0]=__float2bfloat16(v.x); pk.h[j*4+1]=__float2bfloat16(v.y);
      pk.h[j*4+2]=__float2bfloat16(v.z); pk.h[j*4+3]=__float2bfloat16(v.w);
    }
    *(uint4*)(Ws + kr*72 + nseg)     = pk.u[0];
    *(uint4*)(Ws + kr*72 + nseg + 8) = pk.u[1];
    __syncthreads();
    int n = t&63, kseg = t>>6;
    union { uint4 u[2]; bf16 h[16]; } o;
    #pragma unroll
    for (int k=0;k<16;k++) o.h[k] = Ws[(kseg*16+k)*72 + n];
    bf16* dst = Wt + (size_t)(n0+n)*DIM_ + k0 + kseg*16;
    *(uint4*)dst = o.u[0];
    *(uint4*)(dst+8) = o.u[1];
  }
}

// ------------------------------------------------------------- GEMM core
// (kept for gemm_o only) 128x128 tile, BK=32, global_load_lds staging.
__device__ __forceinline__ void gemm_core(
    const bf16* __restrict__ A, const bf16* __restrict__ Bmat,
    const float* __restrict__ bias, const float* __restrict__ residual,
    void* __restrict__ outv, int rows_per_batch, int row_offset,
    int a_batch_stride_rows, int n_seq, float scale,
    int emode, int m0, int n0, char* smem)
{
  bf16* As = (bf16*)smem;            // 128 x 32
  bf16* Bs = (bf16*)(smem + 8192);
  float* Ts = (float*)smem;          // epilogue: 32 rows x stride 132

  const int t = threadIdx.x;
  const int r0 = t>>2, c8 = (t&3)*8;
  int gm0 = m0 + r0, gm1 = m0 + 64 + r0;
  int b0i = gm0 / rows_per_batch, b1i = gm1 / rows_per_batch;
  const bf16* a0 = A + ((size_t)b0i*a_batch_stride_rows + row_offset + (gm0 - b0i*rows_per_batch))*(size_t)DIM_ + c8;
  const bf16* a1 = A + ((size_t)b1i*a_batch_stride_rows + row_offset + (gm1 - b1i*rows_per_batch))*(size_t)DIM_ + c8;
  const bf16* wb0 = Bmat + (size_t)(n0 + r0)*DIM_ + c8;
  const bf16* wb1 = Bmat + (size_t)(n0 + 64 + r0)*DIM_ + c8;
  bf16* lA0 = As + t*8;  bf16* lA1 = As + 64*32 + t*8;
  bf16* lB0 = Bs + t*8;  bf16* lB1 = Bs + 64*32 + t*8;

  const int wave = t>>6, lane = t&63, qq = lane>>4, mr = lane&15;
  const int wm = (wave>>1)*64, wn = (wave&1)*64;

  f32x4 acc[4][4] = {};
  for (int k0 = 0; k0 < DIM_; k0 += 32) {
    gll16(a0 + k0, lA0);
    gll16(a1 + k0, lA1);
    gll16(wb0 + k0, lB0);
    gll16(wb1 + k0, lB1);
    __syncthreads();
    bf16x8 af[4], bfr[4];
    #pragma unroll
    for (int ms=0;ms<4;ms++) af[ms]  = *(const bf16x8*)(As + (wm+ms*16+mr)*32 + qq*8);
    #pragma unroll
    for (int ns=0;ns<4;ns++) bfr[ns] = *(const bf16x8*)(Bs + (wn+ns*16+mr)*32 + qq*8);
    #pragma unroll
    for (int ms=0;ms<4;ms++)
      #pragma unroll
      for (int ns=0;ns<4;ns++)
        acc[ms][ns] = __builtin_amdgcn_mfma_f32_16x16x32_bf16(af[ms], bfr[ns], acc[ms][ns], 0,0,0);
    __syncthreads();
  }

  const int lr = t>>3, cs = (t&7)*16;
  for (int R=0; R<4; R++){
    if ((wave>>1) == (R>>1)) {
      #pragma unroll
      for (int ms2=0; ms2<2; ms2++){
        int ms = (R&1)*2 + ms2;
        #pragma unroll
        for (int ns=0; ns<4; ns++){
          int col = wn + ns*16 + mr;
          #pragma unroll
          for (int r=0;r<4;r++)
            Ts[(ms2*16 + qq*4 + r)*132 + col] = acc[ms][ns][r];
        }
      }
    }
    __syncthreads();
    float v[16];
    #pragma unroll
    for (int j=0;j<4;j++){
      float4 f = *(const float4*)(Ts + lr*132 + cs + j*4);
      v[j*4+0]=f.x; v[j*4+1]=f.y; v[j*4+2]=f.z; v[j*4+3]=f.w;
    }
    int gr = m0 + R*32 + lr;
    int gc = n0 + cs;
    if (emode == 0) {
      float* out = (float*)outv;
      size_t base = (size_t)gr*DIM_ + gc;
      #pragma unroll
      for (int j=0;j<4;j++){
        float4 bv = *(const float4*)(bias + gc + j*4);
        float4 rv = *(const float4*)(residual + base + j*4);
        float4 o4;
        o4.x = v[j*4+0] + bv.x + rv.x;
        o4.y = v[j*4+1] + bv.y + rv.y;
        o4.z = v[j*4+2] + bv.z + rv.z;
        o4.w = v[j*4+3] + bv.w + rv.w;
        *(float4*)(out + base + j*4) = o4;
      }
    } else if (emode == 1) {
      int bb = gr / rows_per_batch;
      int n  = gr - bb*rows_per_batch;
      int hh = gc>>6, dh = gc&63;
      bf16* out = (bf16*)outv + ((size_t)(bb*HEADS + hh)*n_seq + n)*DH + dh;
      union { uint4 u[2]; bf16 h[16]; } pk;
      #pragma unroll
      for (int j=0;j<16;j++) pk.h[j] = __float2bfloat16((v[j] + bias[gc+j])*scale);
      *(uint4*)out     = pk.u[0];
      *(uint4*)(out+8) = pk.u[1];
    } else {
      float bc = bias[gr];
      bf16* out = (bf16*)outv + (size_t)gr*NSEQT + gc;
      union { uint4 u[2]; bf16 h[16]; } pk;
      #pragma unroll
      for (int j=0;j<16;j++) pk.h[j] = __float2bfloat16(v[j] + bc);
      *(uint4*)out     = pk.u[0];
      *(uint4*)(out+8) = pk.u[1];
    }
    __syncthreads();
  }
}

// ---------------------------------------------------------------------------
// 256x256 / BK=64 / 8-wave QKV GEMM, m201-faithful 8-phase schedule.
// 2 K-tiles per iteration, static dbuf. Phase = (m-half, k-half): 16 MFMA,
// reads 8/4/8/4 per tile (each fragment read once). Stages front-loaded
// (4+4 gll16 in the first two phases of each half-iteration) so VMCNT(0)
// at phases 4/8 only drains >=2-phase-old loads. Raw s_barrier pairs,
// setprio around MFMA, NO sched_barrier.
// blocks [0,32): Q. [32,192): K. [192,352): V^T.
// ---------------------------------------------------------------------------
__global__ __launch_bounds__(512, 2) void gemm_qkv2(
    const bf16* __restrict__ X,
    const bf16* __restrict__ WtQ, const bf16* __restrict__ WtK,
    const bf16* __restrict__ WtV,
    const float* __restrict__ bq, const float* __restrict__ bk,
    const float* __restrict__ bv,
    bf16* __restrict__ Qhb, bf16* __restrict__ Khb, bf16* __restrict__ VTg)
{
  __shared__ __align__(16) char smem[131072];
  const int t   = threadIdx.x;
  const int blk = blockIdx.x;

  const bf16 *A, *Bm; const float* bias; bf16* outp;
  int m0, n0, amode, emode, npb, nseq; float scale;
  if (blk < 32) {
    A = X; Bm = WtQ; bias = bq; outp = Qhb;
    m0 = (blk & 7) * 256; n0 = (blk >> 3) * 256;
    amode = 1; emode = 1; npb = NQ; nseq = NQ; scale = SCALE_Q_L2E;
  } else if (blk < 192) {
    int l = blk - 32;
    A = X; Bm = WtK; bias = bk; outp = Khb;
    m0 = (l % 40) * 256; n0 = (l / 40) * 256;
    amode = 0; emode = 1; npb = NT; nseq = NT; scale = 1.0f;
  } else {
    int l = blk - 192;
    A = WtV; Bm = X; bias = bv; outp = VTg;
    m0 = (l / 40) * 256; n0 = (l % 40) * 256;
    amode = 0; emode = 2; npb = DIM_; nseq = 1; scale = 1.0f;
  }

  // ---- staging source pointers (granule-XOR pre-swizzled global addresses)
  const int srow = t >> 3;                 // row within a 64-row chunk
  const int gsw  = (t & 7) ^ (srow & 7);   // swizzled 16B-granule
  const bf16* pA[4]; const bf16* pB[4];
  #pragma unroll
  for (int c = 0; c < 4; ++c) {
    int gm = m0 + c*64 + srow;
    int sr = amode ? ((gm >> 9) * NT + NKV + (gm & (NQ-1))) : gm;
    pA[c] = A  + (size_t)sr * DIM_ + gsw * 8;
    pB[c] = Bm + (size_t)(n0 + c*64 + srow) * DIM_ + gsw * 8;
  }

  const int wave = t >> 6, lane = t & 63;
  const int qq = lane >> 4, mr = lane & 15;
  const int wr = wave >> 2, wc = wave & 3;        // 2M x 4N wave grid
  const int xg0 = ( qq      ^ (mr & 7)) << 4;     // k-half 0 swizzled granule
  const int xg1 = ((4 + qq) ^ (mr & 7)) << 4;     // k-half 1
  const int awb = (wr*128 + mr) * 128;            // A frag row byte base
  const int bwb = (wc*64  + mr) * 128;            // B frag row byte base
  char* const sA = smem;                          // A: 2 x 32 KiB
  char* const sB = smem + 65536;                  // B: 2 x 32 KiB
  const int toff = t * 16;

  f32x4 acc[8][4] = {};

#define ARD(ABASE, MH, XG)                                                    \
  do { _Pragma("unroll")                                                      \
    for (int ms = 0; ms < 4; ++ms)                                            \
      af[ms] = *(const bf16x8*)((ABASE) + awb + (MH)*8192 + ms*2048 + (XG));  \
  } while (0)
#define BRD(BBASE, XG)                                                        \
  do { _Pragma("unroll")                                                      \
    for (int n = 0; n < 4; ++n)                                               \
      bfc[n] = *(const bf16x8*)((BBASE) + bwb + n*2048 + (XG));               \
  } while (0)
#define MM(MH)                                                                \
  do {                                                                        \
    __builtin_amdgcn_s_setprio(1);                                            \
    _Pragma("unroll")                                                         \
    for (int ms = 0; ms < 4; ++ms)                                            \
      _Pragma("unroll")                                                       \
      for (int n = 0; n < 4; ++n)                                             \
        acc[(MH)*4+ms][n] = __builtin_amdgcn_mfma_f32_16x16x32_bf16(          \
            af[ms], bfc[n], acc[(MH)*4+ms][n], 0,0,0);                        \
    __builtin_amdgcn_s_setprio(0);                                            \
  } while (0)
#define STGA(DST, C, KO) gll16(pA[C] + (KO), (bf16*)((DST) + (C)*8192 + toff))
#define STGB(DST, C, KO) gll16(pB[C] + (KO), (bf16*)((DST) + (C)*8192 + toff))

  // ---- prologue: stage tile 0 -> b0 (sA/sB low halves)
  STGA(sA, 0, 0); STGA(sA, 1, 0); STGA(sA, 2, 0); STGA(sA, 3, 0);
  STGB(sB, 0, 0); STGB(sB, 1, 0); STGB(sB, 2, 0); STGB(sB, 3, 0);
  VMCNT(0);
  BAR();

  for (int j = 0; j < 8; ++j) {
    const int ko1 = (2*j + 1) << 6;          // odd tile k-offset (elements)
    const int ko2 = ((2*j + 2) & 15) << 6;   // next even tile (wraps to junk at j=7)
    bf16x8 af[4], bfc[4];

    // ================= tile even (b0: sA, sB) =================
    // P1: af(m0,k0)+bf(k0); stage b1: A0,A1,B0,B1
    ARD(sA, 0, xg0); BRD(sB, xg0);
    STGA(sA + 32768, 0, ko1); STGA(sA + 32768, 1, ko1);
    STGB(sB + 32768, 0, ko1); STGB(sB + 32768, 1, ko1);
    BAR(); MM(0); BAR();
    // P2: af(m1,k0); stage b1: A2,A3,B2,B3
    ARD(sA, 1, xg0);
    STGA(sA + 32768, 2, ko1); STGA(sA + 32768, 3, ko1);
    STGB(sB + 32768, 2, ko1); STGB(sB + 32768, 3, ko1);
    BAR(); MM(1); BAR();
    // P3: af(m0,k1)+bf(k1)
    ARD(sA, 0, xg1); BRD(sB, xg1);
    BAR(); MM(0); BAR();
    // P4: af(m1,k1); wait b1 stages (issued P1-P2, >=2 phases old)
    ARD(sA, 1, xg1);
    VMCNT(0);
    BAR(); MM(1); BAR();

    // ================= tile odd (b1: sA+32K, sB+32K) =================
    // P5: af(m0,k0)+bf(k0); stage next even -> b0: A0,A1,B0,B1
    ARD(sA + 32768, 0, xg0); BRD(sB + 32768, xg0);
    STGA(sA, 0, ko2); STGA(sA, 1, ko2);
    STGB(sB, 0, ko2); STGB(sB, 1, ko2);
    BAR(); MM(0); BAR();
    // P6: af(m1,k0); stage b0: A2,A3,B2,B3
    ARD(sA + 32768, 1, xg0);
    STGA(sA, 2, ko2); STGA(sA, 3, ko2);
    STGB(sB, 2, ko2); STGB(sB, 3, ko2);
    BAR(); MM(1); BAR();
    // P7: af(m0,k1)+bf(k1)
    ARD(sA + 32768, 0, xg1); BRD(sB + 32768, xg1);
    BAR(); MM(0); BAR();
    // P8: af(m1,k1); wait b0 stages (issued P5-P6, >=2 phases old)
    ARD(sA + 32768, 1, xg1);
    VMCNT(0);
    BAR(); MM(1); BAR();
  }

#undef ARD
#undef BRD
#undef MM
#undef STGA
#undef STGB

  // ---- drain junk wrap-stages before repurposing LDS
  VMCNT(0);
  __syncthreads();

  // ---- epilogue: 8 rounds of 32 rows through LDS (stride 264 f32)
  float* Of = (float*)smem;
  const int er = t >> 4, ec = (t & 15) * 16;
  #pragma unroll
  for (int R = 0; R < 8; ++R) {
    if (wr == (R >> 2)) {
      #pragma unroll
      for (int j = 0; j < 2; ++j)
        #pragma unroll
        for (int nf = 0; nf < 4; ++nf)
          #pragma unroll
          for (int r = 0; r < 4; ++r)
            Of[(j*16 + qq*4 + r)*264 + wc*64 + nf*16 + mr] = acc[((R&3)<<1)+j][nf][r];
    }
    __syncthreads();
    {
      int gr = m0 + R*32 + er;
      int gc = n0 + ec;
      float v[16];
      #pragma unroll
      for (int j = 0; j < 4; ++j) {
        float4 f = *(const float4*)(Of + er*264 + ec + j*4);
        v[j*4+0]=f.x; v[j*4+1]=f.y; v[j*4+2]=f.z; v[j*4+3]=f.w;
      }
      if (emode == 1) {
        int bb = gr / npb, n = gr - bb*npb;
        int hh = gc >> 6, dh = gc & 63;
        bf16* o = outp + ((size_t)(bb*HEADS + hh)*nseq + n)*DH + dh;
        union { uint4 u[2]; bf16 h[16]; } pk;
        #pragma unroll
        for (int j = 0; j < 16; ++j) pk.h[j] = __float2bfloat16((v[j] + bias[gc+j])*scale);
        *(uint4*)o     = pk.u[0];
        *(uint4*)(o+8) = pk.u[1];
      } else {
        float bc = bias[gr];
        bf16* o = outp + (size_t)gr*NSEQT + gc;
        union { uint4 u[2]; bf16 h[16]; } pk;
        #pragma unroll
        for (int j = 0; j < 16; ++j) pk.h[j] = __float2bfloat16(v[j] + bc);
        *(uint4*)o     = pk.u[0];
        *(uint4*)(o+8) = pk.u[1];
      }
    }
    __syncthreads();
  }
}

// ------------------------------------------------ output projection GEMM
__global__ __launch_bounds__(256) void gemm_o(
    const bf16* __restrict__ Ctx, const bf16* __restrict__ WtO,
    const float* __restrict__ bo, const float* __restrict__ residual,
    float* __restrict__ out)
{
  __shared__ __align__(16) char smem[16896];
  const int blk = blockIdx.x;
  gemm_core(Ctx, WtO, bo, residual, out, B_*NQ, 0, B_*NQ, NQ, 1.0f, 0,
            (blk&15)*128, (blk>>4)*128, smem);
}

// --------------------------------------------------------------- Attention
// attn6: block = 64 q-rows of one (b,h). Wave w: q-rows (w>>1)*32..+31,
// key half (w&1)*32 of each 64-key tile -> each wave reads HALF the K/V
// LDS bytes of attn5. K staged key-interleaved: LDS row sl <-> key
// 32*(sl>>5) + 2*(sl&15) + ((sl>>4)&1), so lane mr's two scores (subtiles
// g=0,1) are adjacent keys (2mr, 2mr+1) -> one packed word per q-row.
// End: cross-pair O/l merge via LDS, then vectorized store.
__global__ __launch_bounds__(256) void attn6_kernel(
    const bf16* __restrict__ Qh, const bf16* __restrict__ Kh,
    const bf16* __restrict__ VTg, bf16* __restrict__ Ctx)
{
  __shared__ __align__(16) bf16 KV[2][8192];          // 32 KB (2 buffers)
  __shared__ __align__(16) unsigned int Ps[4][640];   // per-wave P: 32 rows x 20 words

  const int t = threadIdx.x, wave = t>>6, lane = t&63;
  const int qq = lane>>4, mr = lane&15;
  const int blk = blockIdx.x;
  const int bh = (blk&7)*8 + (blk>>6);      // same bh -> same blk%8 slot (XCD)
  const int q0 = ((blk>>3)&7)*64;
  const int b = bh>>4, h = bh&15;
  const int pair = wave>>1, kh = wave&1;
  const int qb = pair*32;

  const int sl = t>>2, sc = t&3;
  const int skey = 32*(sl>>5) + 2*(sl&15) + ((sl>>4)&1);
  const bf16* Kb  = Kh + (size_t)bh*NT*DH + (size_t)skey*DH + sc*8;
  const bf16* VbT = VTg + ((size_t)(h*DH) + sl)*NSEQT + (size_t)b*NT + sc*8;

  // Q fragments for this wave's 32 q-rows (two 16-row subtiles)
  bf16x8 qf[2][2];
  #pragma unroll
  for (int mt=0; mt<2; mt++){
    const bf16* Qb = Qh + ((size_t)bh*NQ + q0 + qb + mt*16 + mr)*DH;
    qf[mt][0] = *(const bf16x8*)(Qb + qq*8);
    qf[mt][1] = *(const bf16x8*)(Qb + 32 + qq*8);
  }

  f32x4 o[2][4] = {};
  float l[2][4] = {};
  unsigned int* Pw = &Ps[wave][0];

  // prefetch tile 0 into buffer 0
  {
    bf16* bp = &KV[0][0];
    gll16(Kb,        bp + t*8);
    gll16(Kb + 32,   bp + 2048 + t*8);
    gll16(VbT,       bp + 4096 + t*8);
    gll16(VbT + 32,  bp + 6144 + t*8);
  }

  for (int it = 0; it < NT/64; it++) {
    __syncthreads();
    if (it + 1 < NT/64) {
      int kt = (it+1)*64;
      bf16* bp = &KV[(it+1)&1][0];
      gll16(Kb  + (size_t)kt*DH,      bp + t*8);
      gll16(Kb  + (size_t)kt*DH + 32, bp + 2048 + t*8);
      gll16(VbT + kt,                 bp + 4096 + t*8);
      gll16(VbT + kt + 32,            bp + 6144 + t*8);
    }
    const bf16* cbuf = &KV[it&1][0];

    // K fragments: this wave's key half, 2 subtiles of 16 keys
    bf16x8 kf[2][2];
    #pragma unroll
    for (int g=0; g<2; g++){
      kf[g][0] = *(const bf16x8*)(cbuf + (32*kh + 16*g + mr)*32 + qq*8);
      kf[g][1] = *(const bf16x8*)(cbuf + 2048 + (32*kh + 16*g + mr)*32 + qq*8);
    }
    f32x4 s[2][2];
    #pragma unroll
    for (int mt=0; mt<2; mt++)
      #pragma unroll
      for (int g=0; g<2; g++){
        f32x4 z = {};
        z = __builtin_amdgcn_mfma_f32_16x16x32_bf16(qf[mt][0], kf[g][0], z, 0,0,0);
        z = __builtin_amdgcn_mfma_f32_16x16x32_bf16(qf[mt][1], kf[g][1], z, 0,0,0);
        s[mt][g] = z;
      }
    // V fragments: this wave's key-half panel
    bf16x8 vf[4];
    #pragma unroll
    for (int n2=0; n2<4; n2++)
      vf[n2] = *(const bf16x8*)(cbuf + 4096 + kh*2048 + (n2*16+mr)*32 + qq*8);

    // exp2 + pack pair (keys 2mr, 2mr+1 of the half) -> one word per q-row
    #pragma unroll
    for (int mt=0; mt<2; mt++)
      #pragma unroll
      for (int r=0; r<4; r++){
        float e0 = __builtin_amdgcn_exp2f(s[mt][0][r]);
        float e1 = __builtin_amdgcn_exp2f(s[mt][1][r]);
        l[mt][r] += e0 + e1;
        unsigned a0 = __float_as_uint(e0) + 0x8000u;
        unsigned a1 = __float_as_uint(e1) + 0x8000u;
        Pw[(mt*16 + qq*4 + r)*20 + mr] = __builtin_amdgcn_perm(a1, a0, 0x07060302u);
      }
    asm volatile("s_waitcnt lgkmcnt(0)" ::: "memory");
    bf16x8 pa[2];
    #pragma unroll
    for (int mt=0; mt<2; mt++)
      pa[mt] = *(const bf16x8*)(Pw + (mt*16+mr)*20 + qq*4);
    #pragma unroll
    for (int mt=0; mt<2; mt++)
      #pragma unroll
      for (int n2=0; n2<4; n2++)
        o[mt][n2] = __builtin_amdgcn_mfma_f32_16x16x32_bf16(pa[mt], vf[n2], o[mt][n2], 0,0,0);
  }

  // partial row sums over this wave's key half
  float lsum[2][4];
  #pragma unroll
  for (int mt=0; mt<2; mt++)
    #pragma unroll
    for (int r=0; r<4; r++){
      float v = l[mt][r];
      #pragma unroll
      for (int m=1;m<16;m<<=1) v += __shfl_xor(v, m, 16);
      lsum[mt][r] = v;
    }

  // cross-pair merge via LDS (waves kh=1 publish, kh=0 merge+normalize)
  __syncthreads();
  float* Of  = (float*)&KV[0][0];   // 64 rows x stride 68 f32 (17408 B)
  float* lsh = (float*)&Ps[0][0];   // 64 f32
  if (kh == 1) {
    #pragma unroll
    for (int mt=0; mt<2; mt++){
      #pragma unroll
      for (int n2=0; n2<4; n2++)
        #pragma unroll
        for (int r=0; r<4; r++)
          Of[(qb + mt*16 + qq*4 + r)*68 + n2*16 + mr] = o[mt][n2][r];
      if (mr == 0)
        #pragma unroll
        for (int r=0; r<4; r++)
          lsh[qb + mt*16 + qq*4 + r] = lsum[mt][r];
    }
  }
  __syncthreads();
  if (kh == 0) {
    #pragma unroll
    for (int mt=0; mt<2; mt++)
      #pragma unroll
      for (int r=0; r<4; r++){
        int row = qb + mt*16 + qq*4 + r;
        float rl = 1.0f / (lsum[mt][r] + lsh[row]);
        #pragma unroll
        for (int n2=0; n2<4; n2++){
          int idx = row*68 + n2*16 + mr;
          Of[idx] = (o[mt][n2][r] + Of[idx]) * rl;
        }
      }
  }
  __syncthreads();
  // vectorized store: each thread writes 16 bf16 of one row
  {
    int row = t>>2, seg = (t&3)*16;
    union { uint4 u[2]; bf16 hh[16]; } pkv;
    #pragma unroll
    for (int j=0;j<16;j++) pkv.hh[j] = __float2bfloat16(Of[row*68 + seg + j]);
    bf16* dst = Ctx + ((size_t)b*NQ + q0 + row)*DIM_ + h*DH + seg;
    *(uint4*)dst = pkv.u[0];
    *(uint4*)(dst+8) = pkv.u[1];
  }
}

// ------------------------------------------------------------------ launch
extern "C" void kernel_launch(void* const* d_in, const int* in_sizes, int n_in,
                              void* d_out, int out_size, void* d_ws, size_t ws_size,
                              hipStream_t stream)
{
  const float* query  = (const float*)d_in[0];
  const float* kv     = (const float*)d_in[1];
  const float* ln_q_g = (const float*)d_in[2];
  const float* ln_q_b = (const float*)d_in[3];
  const float* ln_kv_g= (const float*)d_in[4];
  const float* ln_kv_b= (const float*)d_in[5];
  const float* Wq = (const float*)d_in[6];
  const float* bq = (const float*)d_in[7];
  const float* Wk = (const float*)d_in[8];
  const float* bk = (const float*)d_in[9];
  const float* Wv = (const float*)d_in[10];
  const float* bv = (const float*)d_in[11];
  const float* Wo = (const float*)d_in[12];
  const float* bo = (const float*)d_in[13];
  float* out = (float*)d_out;

  char* ws = (char*)d_ws;
  size_t off = 0;
  auto take = [&](size_t bytes)->char* {
    char* p = ws + off; off += (bytes + 255) & ~(size_t)255; return p;
  };
  bf16* X    = (bf16*)take((size_t)B_*NT*DIM_*2);   // LN output (concat kv|q)
  bf16* Qhb  = (bf16*)take((size_t)B_*NQ*DIM_*2);   // head-major, pre-scaled
  bf16* Khb  = (bf16*)take((size_t)B_*NT*DIM_*2);   // head-major
  bf16* VTg  = (bf16*)take((size_t)DIM_*NSEQT*2);   // V^T [ch][b*NT+n]
  bf16* Ctx  = (bf16*)take((size_t)B_*NQ*DIM_*2);
  bf16* WtQ  = (bf16*)take((size_t)DIM_*DIM_*2);
  bf16* WtK  = (bf16*)take((size_t)DIM_*DIM_*2);
  bf16* WtV  = (bf16*)take((size_t)DIM_*DIM_*2);
  bf16* WtO  = (bf16*)take((size_t)DIM_*DIM_*2);

  prep_kernel<<<B_*NT + 1024, 256, 0, stream>>>(
      query, kv, ln_q_g, ln_q_b, ln_kv_g, ln_kv_b, X,
      Wq, Wk, Wv, Wo, WtQ, WtK, WtV, WtO);

  gemm_qkv2<<<352, 512, 0, stream>>>(X, WtQ, WtK, WtV, bq, bk, bv,
                                     Qhb, Khb, VTg);

  attn6_kernel<<<512, 256, 0, stream>>>(Qhb, Khb, VTg, Ctx);

  gemm_o<<<128, 256, 0, stream>>>(Ctx, WtO, bo, query, out);
}

// Round 3
// 234.040 us; speedup vs baseline: 1.1687x; 1.1687x over previous
//
#include <hip/hip_runtime.h>
#include <hip/hip_bf16.h>

#define B_    4
#define NQ    512
#define NKV   2048
#define NT    2560     // NKV + NQ
#define DIM_  1024
#define HEADS 16
#define DH    64
#define NSEQT 10240    // B_*NT
// SCALE * log2(e): attention uses raw exp2
#define SCALE_Q_L2E 0.18033688011112042f

typedef short bf16x8 __attribute__((ext_vector_type(8)));
typedef float f32x4  __attribute__((ext_vector_type(4)));
typedef __hip_bfloat16 bf16;

// async global->LDS, 16B per lane. Global side may be a per-lane gather;
// LDS side is wave-uniform base + lane*16.
__device__ inline void gll16(const bf16* g, bf16* l) {
  __builtin_amdgcn_global_load_lds(
      (const __attribute__((address_space(1))) unsigned int*)g,
      (__attribute__((address_space(3))) unsigned int*)l, 16, 0, 0);
}

#define VMCNT(n) asm volatile("s_waitcnt vmcnt(" #n ")" ::: "memory")
#define BAR() __builtin_amdgcn_s_barrier()

// ---------------------------------------------- fused LayerNorm + weight^T
// blocks [0, B_*NT): LN rows -> X.  blocks [B_*NT, +1024): 4x trw 64x64 tiles.
__global__ __launch_bounds__(256) void prep_kernel(
    const float* __restrict__ query, const float* __restrict__ kv,
    const float* __restrict__ lgq, const float* __restrict__ lbq,
    const float* __restrict__ lgkv, const float* __restrict__ lbkv,
    bf16* __restrict__ X,
    const float* __restrict__ W0, const float* __restrict__ W1,
    const float* __restrict__ W2, const float* __restrict__ W3,
    bf16* __restrict__ T0, bf16* __restrict__ T1,
    bf16* __restrict__ T2, bf16* __restrict__ T3)
{
  __shared__ __align__(16) char psm[9216];
  const int t = threadIdx.x;
  const int blkid = blockIdx.x;
  if (blkid < B_*NT) {
    float* sh = (float*)psm;
    int b = blkid / NT, r = blkid % NT;
    const float *src, *g, *bb;
    if (r < NKV) { src = kv    + ((size_t)b*NKV + r)*DIM_;      g = lgkv; bb = lbkv; }
    else         { src = query + ((size_t)b*NQ + (r-NKV))*DIM_; g = lgq;  bb = lbq;  }
    float4 v = ((const float4*)src)[t];
    float s  = v.x+v.y+v.z+v.w;
    float s2 = v.x*v.x+v.y*v.y+v.z*v.z+v.w*v.w;
    #pragma unroll
    for (int m=1;m<64;m<<=1){ s += __shfl_xor(s,m,64); s2 += __shfl_xor(s2,m,64); }
    int wave=t>>6, lane=t&63;
    if(lane==0){ sh[wave]=s; sh[4+wave]=s2; }
    __syncthreads();
    s  = sh[0]+sh[1]+sh[2]+sh[3];
    s2 = sh[4]+sh[5]+sh[6]+sh[7];
    float mu = s*(1.0f/DIM_);
    float rs = rsqrtf(s2*(1.0f/DIM_) - mu*mu + 1e-5f);
    float4 gg = ((const float4*)g)[t];
    float4 b4 = ((const float4*)bb)[t];
    bf16* dst = X + (size_t)blkid*DIM_ + t*4;
    dst[0]=__float2bfloat16((v.x-mu)*rs*gg.x + b4.x);
    dst[1]=__float2bfloat16((v.y-mu)*rs*gg.y + b4.y);
    dst[2]=__float2bfloat16((v.z-mu)*rs*gg.z + b4.z);
    dst[3]=__float2bfloat16((v.w-mu)*rs*gg.w + b4.w);
  } else {
    int l = blkid - B_*NT;
    const float* W; bf16* Wt;
    switch (l>>8) {
      case 0: W=W0; Wt=T0; break;
      case 1: W=W1; Wt=T1; break;
      case 2: W=W2; Wt=T2; break;
      default: W=W3; Wt=T3; break;
    }
    int rem = l & 255;
    int k0 = (rem&15)*64, n0 = (rem>>4)*64;
    bf16* Ws = (bf16*)psm;            // 64 x 72
    int kr = t>>2, nseg = (t&3)*16;
    const float4* s4 = (const float4*)(W + (size_t)(k0+kr)*DIM_ + n0 + nseg);
    union { uint4 u[2]; bf16 h[16]; } pk;
    #pragma unroll
    for (int j=0;j<4;j++){
      float4 v = s4[j];
      pk.h[j*4+0]=__float2bfloat16(v.x); pk.h[j*4+1]=__float2bfloat16(v.y);
      pk.h[j*4+2]=__float2bfloat16(v.z); pk.h[j*4+3]=__float2bfloat16(v.w);
    }
    *(uint4*)(Ws + kr*72 + nseg)     = pk.u[0];
    *(uint4*)(Ws + kr*72 + nseg + 8) = pk.u[1];
    __syncthreads();
    int n = t&63, kseg = t>>6;
    union { uint4 u[2]; bf16 h[16]; } o;
    #pragma unroll
    for (int k=0;k<16;k++) o.h[k] = Ws[(kseg*16+k)*72 + n];
    bf16* dst = Wt + (size_t)(n0+n)*DIM_ + k0 + kseg*16;
    *(uint4*)dst = o.u[0];
    *(uint4*)(dst+8) = o.u[1];
  }
}

// ------------------------------------------------------------- GEMM core v2
// 128x128 tile, BK=64, 4 waves (2x2), double-buffered 64 KiB LDS, granule-XOR
// swizzle (conflict-free ds_read_b128), one vmcnt(0)+s_barrier per K-tile,
// stages issued at tile top. Designed for 2 blocks/CU residency (TLP hides
// the staging latency that a single lockstep block cannot).
// LDS layout: [row 0..127][granule 0..7], LDS[row][g] = global[row][g^(row&7)].
__device__ __forceinline__ void gemm_core2(
    const bf16* __restrict__ A, const bf16* __restrict__ Bmat,
    const float* __restrict__ bias, const float* __restrict__ residual,
    void* __restrict__ outv, int rows_per_batch, int row_offset,
    int a_batch_stride_rows, int n_seq, float scale,
    int emode, int m0, int n0, char* smem)
{
  char* const sA = smem;             // 2 x 16384
  char* const sB = smem + 32768;     // 2 x 16384
  float* Ts = (float*)smem;          // epilogue: 32 rows x stride 132

  const int t = threadIdx.x;
  const int srow = t >> 3;                 // 0..31: row within 32-row chunk
  const int gsw  = (t & 7) ^ (srow & 7);   // pre-swizzled source granule
  const bf16* pA[4]; const bf16* pB[4];
  #pragma unroll
  for (int c = 0; c < 4; ++c) {
    int gm = m0 + c*32 + srow;
    int bi = gm / rows_per_batch;
    pA[c] = A + ((size_t)bi*a_batch_stride_rows + row_offset
                 + (gm - bi*rows_per_batch))*(size_t)DIM_ + gsw*8;
    pB[c] = Bmat + (size_t)(n0 + c*32 + srow)*(size_t)DIM_ + gsw*8;
  }
  const int toff = t*16;

  const int wave = t>>6, lane = t&63, qq = lane>>4, mr = lane&15;
  const int wm = (wave>>1)*64, wn = (wave&1)*64;
  // fragment read byte offset within a row: granule (kh*4+qq) ^ (row&7);
  // row&7 == mr&7 for all fragment rows (wm, ms*16 are multiples of 8).
  const int xq0 = (( qq    ) ^ (mr&7)) << 4;
  const int xq1 = ((4 + qq ) ^ (mr&7)) << 4;

  f32x4 acc[4][4] = {};

  // prologue: stage tile 0 -> buffer 0
  #pragma unroll
  for (int c=0;c<4;++c) gll16(pA[c], (bf16*)(sA + c*4096 + toff));
  #pragma unroll
  for (int c=0;c<4;++c) gll16(pB[c], (bf16*)(sB + c*4096 + toff));
  VMCNT(0);
  BAR();

  for (int kt = 0; kt < 16; ++kt) {
    const int cb = (kt&1) << 14;
    const int nb = ((kt+1)&1) << 14;
    if (kt < 15) {
      const int ko = (kt+1)*64;
      #pragma unroll
      for (int c=0;c<4;++c) gll16(pA[c] + ko, (bf16*)(sA + nb + c*4096 + toff));
      #pragma unroll
      for (int c=0;c<4;++c) gll16(pB[c] + ko, (bf16*)(sB + nb + c*4096 + toff));
    }
    #pragma unroll
    for (int kh = 0; kh < 2; ++kh) {
      const int xq = kh ? xq1 : xq0;
      bf16x8 af[4], bfr[4];
      #pragma unroll
      for (int ms=0; ms<4; ++ms)
        af[ms]  = *(const bf16x8*)(sA + cb + (wm + ms*16 + mr)*128 + xq);
      #pragma unroll
      for (int ns=0; ns<4; ++ns)
        bfr[ns] = *(const bf16x8*)(sB + cb + (wn + ns*16 + mr)*128 + xq);
      __builtin_amdgcn_s_setprio(1);
      #pragma unroll
      for (int ms=0; ms<4; ++ms)
        #pragma unroll
        for (int ns=0; ns<4; ++ns)
          acc[ms][ns] = __builtin_amdgcn_mfma_f32_16x16x32_bf16(
              af[ms], bfr[ns], acc[ms][ns], 0,0,0);
      __builtin_amdgcn_s_setprio(0);
    }
    VMCNT(0);   // own-wave next-tile stages landed; barrier joins all waves
    BAR();
  }
  __syncthreads();

  // epilogue: 4 rounds of 32 rows through LDS
  const int lr = t>>3, cs = (t&7)*16;
  for (int R=0; R<4; R++){
    if ((wave>>1) == (R>>1)) {
      #pragma unroll
      for (int ms2=0; ms2<2; ms2++){
        int ms = (R&1)*2 + ms2;
        #pragma unroll
        for (int ns=0; ns<4; ns++){
          int col = wn + ns*16 + mr;
          #pragma unroll
          for (int r=0;r<4;r++)
            Ts[(ms2*16 + qq*4 + r)*132 + col] = acc[ms][ns][r];
        }
      }
    }
    __syncthreads();
    float v[16];
    #pragma unroll
    for (int j=0;j<4;j++){
      float4 f = *(const float4*)(Ts + lr*132 + cs + j*4);
      v[j*4+0]=f.x; v[j*4+1]=f.y; v[j*4+2]=f.z; v[j*4+3]=f.w;
    }
    int gr = m0 + R*32 + lr;
    int gc = n0 + cs;
    if (emode == 0) {
      float* out = (float*)outv;
      size_t base = (size_t)gr*DIM_ + gc;
      #pragma unroll
      for (int j=0;j<4;j++){
        float4 bv = *(const float4*)(bias + gc + j*4);
        float4 rv = *(const float4*)(residual + base + j*4);
        float4 o4;
        o4.x = v[j*4+0] + bv.x + rv.x;
        o4.y = v[j*4+1] + bv.y + rv.y;
        o4.z = v[j*4+2] + bv.z + rv.z;
        o4.w = v[j*4+3] + bv.w + rv.w;
        *(float4*)(out + base + j*4) = o4;
      }
    } else if (emode == 1) {
      int bb = gr / rows_per_batch;
      int n  = gr - bb*rows_per_batch;
      int hh = gc>>6, dh = gc&63;
      bf16* out = (bf16*)outv + ((size_t)(bb*HEADS + hh)*n_seq + n)*DH + dh;
      union { uint4 u[2]; bf16 h[16]; } pk;
      #pragma unroll
      for (int j=0;j<16;j++) pk.h[j] = __float2bfloat16((v[j] + bias[gc+j])*scale);
      *(uint4*)out     = pk.u[0];
      *(uint4*)(out+8) = pk.u[1];
    } else {
      float bc = bias[gr];
      bf16* out = (bf16*)outv + (size_t)gr*NSEQT + gc;
      union { uint4 u[2]; bf16 h[16]; } pk;
      #pragma unroll
      for (int j=0;j<16;j++) pk.h[j] = __float2bfloat16(v[j] + bc);
      *(uint4*)out     = pk.u[0];
      *(uint4*)(out+8) = pk.u[1];
    }
    __syncthreads();
  }
}

// -------------------------------------------- fused Q/K/V projection GEMMs
// blocks [0,128): Q. [128,768): K (m fastest; same-m n-blocks are 80 apart
// = 0 mod 8 -> same XCD -> A-panel L2 reuse). [768,1408): V^T (n fastest,
// same property for the X panels on the B side).
__global__ __launch_bounds__(256) void gemm_qkv3(
    const bf16* __restrict__ X,
    const bf16* __restrict__ WtQ, const bf16* __restrict__ WtK,
    const bf16* __restrict__ WtV,
    const float* __restrict__ bq, const float* __restrict__ bk,
    const float* __restrict__ bv,
    bf16* __restrict__ Qhb, bf16* __restrict__ Khb, bf16* __restrict__ VTg)
{
  __shared__ __align__(16) char smem[65536];
  const int blk = blockIdx.x;
  if (blk < 128) {
    gemm_core2(X, WtQ, bq, nullptr, Qhb, NQ, NKV, NT, NQ, SCALE_Q_L2E, 1,
               (blk&15)*128, (blk>>4)*128, smem);
  } else if (blk < 768) {
    int l = blk - 128;
    gemm_core2(X, WtK, bk, nullptr, Khb, NT, 0, NT, NT, 1.0f, 1,
               (l%80)*128, (l/80)*128, smem);
  } else {
    int l = blk - 768;
    gemm_core2(WtV, X, bv, nullptr, VTg, DIM_, 0, DIM_, NSEQT, 1.0f, 2,
               (l/80)*128, (l%80)*128, smem);
  }
}

// ------------------------------------------------ output projection GEMM
__global__ __launch_bounds__(256) void gemm_o(
    const bf16* __restrict__ Ctx, const bf16* __restrict__ WtO,
    const float* __restrict__ bo, const float* __restrict__ residual,
    float* __restrict__ out)
{
  __shared__ __align__(16) char smem[65536];
  const int blk = blockIdx.x;
  gemm_core2(Ctx, WtO, bo, residual, out, B_*NQ, 0, B_*NQ, NQ, 1.0f, 0,
             (blk&15)*128, (blk>>4)*128, smem);
}

// --------------------------------------------------------------- Attention
// attn6: block = 64 q-rows of one (b,h). Wave w: q-rows (w>>1)*32..+31,
// key half (w&1)*32 of each 64-key tile -> each wave reads HALF the K/V
// LDS bytes of attn5. K staged key-interleaved: LDS row sl <-> key
// 32*(sl>>5) + 2*(sl&15) + ((sl>>4)&1), so lane mr's two scores (subtiles
// g=0,1) are adjacent keys (2mr, 2mr+1) -> one packed word per q-row.
// End: cross-pair O/l merge via LDS, then vectorized store.
__global__ __launch_bounds__(256) void attn6_kernel(
    const bf16* __restrict__ Qh, const bf16* __restrict__ Kh,
    const bf16* __restrict__ VTg, bf16* __restrict__ Ctx)
{
  __shared__ __align__(16) bf16 KV[2][8192];          // 32 KB (2 buffers)
  __shared__ __align__(16) unsigned int Ps[4][640];   // per-wave P: 32 rows x 20 words

  const int t = threadIdx.x, wave = t>>6, lane = t&63;
  const int qq = lane>>4, mr = lane&15;
  const int blk = blockIdx.x;
  const int bh = (blk&7)*8 + (blk>>6);      // same bh -> same blk%8 slot (XCD)
  const int q0 = ((blk>>3)&7)*64;
  const int b = bh>>4, h = bh&15;
  const int pair = wave>>1, kh = wave&1;
  const int qb = pair*32;

  const int sl = t>>2, sc = t&3;
  const int skey = 32*(sl>>5) + 2*(sl&15) + ((sl>>4)&1);
  const bf16* Kb  = Kh + (size_t)bh*NT*DH + (size_t)skey*DH + sc*8;
  const bf16* VbT = VTg + ((size_t)(h*DH) + sl)*NSEQT + (size_t)b*NT + sc*8;

  // Q fragments for this wave's 32 q-rows (two 16-row subtiles)
  bf16x8 qf[2][2];
  #pragma unroll
  for (int mt=0; mt<2; mt++){
    const bf16* Qb = Qh + ((size_t)bh*NQ + q0 + qb + mt*16 + mr)*DH;
    qf[mt][0] = *(const bf16x8*)(Qb + qq*8);
    qf[mt][1] = *(const bf16x8*)(Qb + 32 + qq*8);
  }

  f32x4 o[2][4] = {};
  float l[2][4] = {};
  unsigned int* Pw = &Ps[wave][0];

  // prefetch tile 0 into buffer 0
  {
    bf16* bp = &KV[0][0];
    gll16(Kb,        bp + t*8);
    gll16(Kb + 32,   bp + 2048 + t*8);
    gll16(VbT,       bp + 4096 + t*8);
    gll16(VbT + 32,  bp + 6144 + t*8);
  }

  for (int it = 0; it < NT/64; it++) {
    __syncthreads();
    if (it + 1 < NT/64) {
      int kt = (it+1)*64;
      bf16* bp = &KV[(it+1)&1][0];
      gll16(Kb  + (size_t)kt*DH,      bp + t*8);
      gll16(Kb  + (size_t)kt*DH + 32, bp + 2048 + t*8);
      gll16(VbT + kt,                 bp + 4096 + t*8);
      gll16(VbT + kt + 32,            bp + 6144 + t*8);
    }
    const bf16* cbuf = &KV[it&1][0];

    // K fragments: this wave's key half, 2 subtiles of 16 keys
    bf16x8 kf[2][2];
    #pragma unroll
    for (int g=0; g<2; g++){
      kf[g][0] = *(const bf16x8*)(cbuf + (32*kh + 16*g + mr)*32 + qq*8);
      kf[g][1] = *(const bf16x8*)(cbuf + 2048 + (32*kh + 16*g + mr)*32 + qq*8);
    }
    f32x4 s[2][2];
    #pragma unroll
    for (int mt=0; mt<2; mt++)
      #pragma unroll
      for (int g=0; g<2; g++){
        f32x4 z = {};
        z = __builtin_amdgcn_mfma_f32_16x16x32_bf16(qf[mt][0], kf[g][0], z, 0,0,0);
        z = __builtin_amdgcn_mfma_f32_16x16x32_bf16(qf[mt][1], kf[g][1], z, 0,0,0);
        s[mt][g] = z;
      }
    // V fragments: this wave's key-half panel
    bf16x8 vf[4];
    #pragma unroll
    for (int n2=0; n2<4; n2++)
      vf[n2] = *(const bf16x8*)(cbuf + 4096 + kh*2048 + (n2*16+mr)*32 + qq*8);

    // exp2 + pack pair (keys 2mr, 2mr+1 of the half) -> one word per q-row
    #pragma unroll
    for (int mt=0; mt<2; mt++)
      #pragma unroll
      for (int r=0; r<4; r++){
        float e0 = __builtin_amdgcn_exp2f(s[mt][0][r]);
        float e1 = __builtin_amdgcn_exp2f(s[mt][1][r]);
        l[mt][r] += e0 + e1;
        unsigned a0 = __float_as_uint(e0) + 0x8000u;
        unsigned a1 = __float_as_uint(e1) + 0x8000u;
        Pw[(mt*16 + qq*4 + r)*20 + mr] = __builtin_amdgcn_perm(a1, a0, 0x07060302u);
      }
    asm volatile("s_waitcnt lgkmcnt(0)" ::: "memory");
    bf16x8 pa[2];
    #pragma unroll
    for (int mt=0; mt<2; mt++)
      pa[mt] = *(const bf16x8*)(Pw + (mt*16+mr)*20 + qq*4);
    #pragma unroll
    for (int mt=0; mt<2; mt++)
      #pragma unroll
      for (int n2=0; n2<4; n2++)
        o[mt][n2] = __builtin_amdgcn_mfma_f32_16x16x32_bf16(pa[mt], vf[n2], o[mt][n2], 0,0,0);
  }

  // partial row sums over this wave's key half
  float lsum[2][4];
  #pragma unroll
  for (int mt=0; mt<2; mt++)
    #pragma unroll
    for (int r=0; r<4; r++){
      float v = l[mt][r];
      #pragma unroll
      for (int m=1;m<16;m<<=1) v += __shfl_xor(v, m, 16);
      lsum[mt][r] = v;
    }

  // cross-pair merge via LDS (waves kh=1 publish, kh=0 merge+normalize)
  __syncthreads();
  float* Of  = (float*)&KV[0][0];   // 64 rows x stride 68 f32 (17408 B)
  float* lsh = (float*)&Ps[0][0];   // 64 f32
  if (kh == 1) {
    #pragma unroll
    for (int mt=0; mt<2; mt++){
      #pragma unroll
      for (int n2=0; n2<4; n2++)
        #pragma unroll
        for (int r=0; r<4; r++)
          Of[(qb + mt*16 + qq*4 + r)*68 + n2*16 + mr] = o[mt][n2][r];
      if (mr == 0)
        #pragma unroll
        for (int r=0; r<4; r++)
          lsh[qb + mt*16 + qq*4 + r] = lsum[mt][r];
    }
  }
  __syncthreads();
  if (kh == 0) {
    #pragma unroll
    for (int mt=0; mt<2; mt++)
      #pragma unroll
      for (int r=0; r<4; r++){
        int row = qb + mt*16 + qq*4 + r;
        float rl = 1.0f / (lsum[mt][r] + lsh[row]);
        #pragma unroll
        for (int n2=0; n2<4; n2++){
          int idx = row*68 + n2*16 + mr;
          Of[idx] = (o[mt][n2][r] + Of[idx]) * rl;
        }
      }
  }
  __syncthreads();
  // vectorized store: each thread writes 16 bf16 of one row
  {
    int row = t>>2, seg = (t&3)*16;
    union { uint4 u[2]; bf16 hh[16]; } pkv;
    #pragma unroll
    for (int j=0;j<16;j++) pkv.hh[j] = __float2bfloat16(Of[row*68 + seg + j]);
    bf16* dst = Ctx + ((size_t)b*NQ + q0 + row)*DIM_ + h*DH + seg;
    *(uint4*)dst = pkv.u[0];
    *(uint4*)(dst+8) = pkv.u[1];
  }
}

// ------------------------------------------------------------------ launch
extern "C" void kernel_launch(void* const* d_in, const int* in_sizes, int n_in,
                              void* d_out, int out_size, void* d_ws, size_t ws_size,
                              hipStream_t stream)
{
  const float* query  = (const float*)d_in[0];
  const float* kv     = (const float*)d_in[1];
  const float* ln_q_g = (const float*)d_in[2];
  const float* ln_q_b = (const float*)d_in[3];
  const float* ln_kv_g= (const float*)d_in[4];
  const float* ln_kv_b= (const float*)d_in[5];
  const float* Wq = (const float*)d_in[6];
  const float* bq = (const float*)d_in[7];
  const float* Wk = (const float*)d_in[8];
  const float* bk = (const float*)d_in[9];
  const float* Wv = (const float*)d_in[10];
  const float* bv = (const float*)d_in[11];
  const float* Wo = (const float*)d_in[12];
  const float* bo = (const float*)d_in[13];
  float* out = (float*)d_out;

  char* ws = (char*)d_ws;
  size_t off = 0;
  auto take = [&](size_t bytes)->char* {
    char* p = ws + off; off += (bytes + 255) & ~(size_t)255; return p;
  };
  bf16* X    = (bf16*)take((size_t)B_*NT*DIM_*2);   // LN output (concat kv|q)
  bf16* Qhb  = (bf16*)take((size_t)B_*NQ*DIM_*2);   // head-major, pre-scaled
  bf16* Khb  = (bf16*)take((size_t)B_*NT*DIM_*2);   // head-major
  bf16* VTg  = (bf16*)take((size_t)DIM_*NSEQT*2);   // V^T [ch][b*NT+n]
  bf16* Ctx  = (bf16*)take((size_t)B_*NQ*DIM_*2);
  bf16* WtQ  = (bf16*)take((size_t)DIM_*DIM_*2);
  bf16* WtK  = (bf16*)take((size_t)DIM_*DIM_*2);
  bf16* WtV  = (bf16*)take((size_t)DIM_*DIM_*2);
  bf16* WtO  = (bf16*)take((size_t)DIM_*DIM_*2);

  prep_kernel<<<B_*NT + 1024, 256, 0, stream>>>(
      query, kv, ln_q_g, ln_q_b, ln_kv_g, ln_kv_b, X,
      Wq, Wk, Wv, Wo, WtQ, WtK, WtV, WtO);

  gemm_qkv3<<<1408, 256, 0, stream>>>(X, WtQ, WtK, WtV, bq, bk, bv,
                                      Qhb, Khb, VTg);

  attn6_kernel<<<512, 256, 0, stream>>>(Qhb, Khb, VTg, Ctx);

  gemm_o<<<128, 256, 0, stream>>>(Ctx, WtO, bo, query, out);
}